// Round 1
// baseline (255.350 us; speedup 1.0000x reference)
//
#include <hip/hip_runtime.h>

// Blocks SNN forward: T=1024, TB=8, B=32, N=1024.
// One thread per (b,n) chain; 128 sequential time-blocks per thread.
// f64 state matches the harness's float64 reference on every heaviside
// decision (fp32 reassociation flips ~1e-7 margins).
//
// R8: first-spike closed form + zero-LDS direct access.
//  * z[t] = sum_{s<=t}(t-s+1) f[s]  =>  z==1 only at the FIRST set bit of f,
//    z==0 strictly before it, z>1 strictly after. So the whole per-t
//    cumsum/select/stat pipeline collapses to: pack fbits -> v_ffbl ->
//    decay = first^7, ssum = p^(first+1), refractory mask = (1<<first)-1,
//    spike store = one-hot at first. Integer-exact vs reference.
//  * LDS transposes removed: per-lane scalar dword loads/stores at
//    x[row*BN + gid] are fully coalesced (64 lanes x 4B = 256B dense per
//    instruction). Removes both per-block lgkm wait points (~2x120cyc of
//    the 1-wave serial path) and 20 ds ops per block.
//  * Membrane/vth/a-update arithmetic is expression-identical to the
//    previous passing kernel (absmax 0.0) - only the integer bookkeeping
//    and the data movement changed.
// Occupancy is grid-bound (32768 chains / 64 = 512 waves = 2/CU), so VGPRs
// are free; PF=4 rotating register frames (32 VGPRs) keep loads ~4 block
// bodies (>3000 cyc) ahead of use, well past HBM latency.

constexpr int T_LEN = 1024;
constexpr int TB    = 8;
constexpr int NBLK  = T_LEN / TB;   // 128
constexpr int BATCH = 32;
constexpr int NOUT  = 1024;
constexpr int BN    = BATCH * NOUT; // 32768 chains
constexpr int PF    = 4;            // prefetch depth (blocks)

__global__ __launch_bounds__(64, 1)
void snn_blocks_kernel(const float* __restrict__ x,
                       const float* __restrict__ beta_raw,
                       const float* __restrict__ p_raw,
                       const float* __restrict__ b_raw,
                       float* __restrict__ out)
{
    const int lane = threadIdx.x;
    const int gid  = blockIdx.x * 64 + lane;   // = b*NOUT + n
    const int n    = gid & (NOUT - 1);

    // clamped properties (f64)
    double beta = (double)beta_raw[n];
    beta = beta < 0.001 ? 0.001 : (beta > 0.999 ? 0.999 : beta);
    double p = fabs((double)p_raw[n]);
    p = p > 0.999 ? 0.999 : p;
    double bb = fabs((double)b_raw[n]);
    bb = bb < 0.001 ? 0.001 : (bb > 1.0 ? 1.0 : bb);
    const double inv_p = 1.0 / p;

    double ppow[9];                 // p^0 .. p^8 (compile-time indexed only)
    ppow[0] = 1.0;
#pragma unroll
    for (int i = 1; i <= 8; ++i) ppow[i] = ppow[i - 1] * p;

    double bbp[8];                  // bb * p^(t+1)
#pragma unroll
    for (int t = 0; t < 8; ++t) bbp[t] = bb * ppow[t + 1];

    const double pp2 = ppow[2], pp4 = ppow[4], pp8 = ppow[8];

    // carry state
    double m = 0.0;                 // running membrane / int_mem
    double a = 0.0;                 // a_kernel scalar (a_k[t] = p^(t+1)*a)
    int maskf  = 0;                 // any spike (z==1) in prev block
    int firstp = 0;                 // first-spike index of prev block

    // rotating register frame file (constant-indexed after unrolling)
    float fr[PF][8];
    const float* xb = x + gid;
    float* ob       = out + gid;

    // preamble: issue loads for blocks 0..PF-1 (8 coalesced dwords each)
#pragma unroll
    for (int k = 0; k < PF; ++k)
#pragma unroll
        for (int t = 0; t < 8; ++t)
            fr[k][t] = xb[(ptrdiff_t)(k * TB + t) * BN];

#pragma unroll 1
    for (int r = 0; r < NBLK / PF; ++r) {
#pragma unroll
        for (int i = 0; i < PF; ++i) {
            const int blk = r * PF + i;

            // ---- header: adaptation update from prev-block stats ----
            // ssum = p^(firstp+1); p^decay with decay = 7-firstp = firstp^7
            double pf1 = p;                        // -> p^(firstp+1)
            pf1 *= (firstp & 1) ? p   : 1.0;
            pf1 *= (firstp & 2) ? pp2 : 1.0;
            pf1 *= (firstp & 4) ? pp4 : 1.0;
            const int dsteps = firstp ^ 7;         // 7 - firstp
            double pd = (dsteps & 1) ? p : 1.0;
            pd *= (dsteps & 2) ? pp2 : 1.0;
            pd *= (dsteps & 4) ? pp4 : 1.0;
            const double new_a = (a * pf1 + inv_p) * pd;
            double vinit;
            if (maskf) { a = new_a;   vinit = 0.0; }  // v_init = 0
            else       { a = pp8 * a; vinit = m;   }  // keep int_mem

            // refractory mask: prev z[t]==0  <=>  t < firstp (when maskf)
            const int zmask = maskf ? ((1 << firstp) - 1) : 0;

            int fbits = 0;
            double mm = vinit;
#pragma unroll
            for (int t = 0; t < 8; ++t) {
                const float xf = ((zmask >> t) & 1) ? 0.0f : fr[i][t];
                mm = beta * mm + (double)xf;           // causal decayed sum
                const double vth = 1.0 + bbp[t] * a;   // 1 + bb*p^(t+1)*a
                fbits |= (mm - vth > 0.0) ? (1 << t) : 0;  // heaviside
            }
            m = mm;
            maskf  = (fbits != 0);
            firstp = fbits ? __builtin_ctz(fbits) : 0;

            // ---- store spikes: one-hot at first set bit (coalesced nt) ----
#pragma unroll
            for (int t = 0; t < 8; ++t) {
                const float sv = (maskf && t == firstp) ? 1.0f : 0.0f;
                __builtin_nontemporal_store(
                    sv, ob + (ptrdiff_t)(blk * TB + t) * BN);
            }

            // ---- prefetch block blk+PF into this frame slot ----
            const int pfb = blk + PF;
            if (pfb < NBLK) {
#pragma unroll
                for (int t = 0; t < 8; ++t)
                    fr[i][t] = xb[(ptrdiff_t)(pfb * TB + t) * BN];
            }
            __builtin_amdgcn_sched_barrier(0);
        }
    }
}

extern "C" void kernel_launch(void* const* d_in, const int* in_sizes, int n_in,
                              void* d_out, int out_size, void* d_ws, size_t ws_size,
                              hipStream_t stream) {
    const float* x        = (const float*)d_in[0];
    const float* beta_raw = (const float*)d_in[1];
    const float* p_raw    = (const float*)d_in[2];
    const float* b_raw    = (const float*)d_in[3];
    float* out            = (float*)d_out;

    dim3 grid(BN / 64);   // 512 workgroups of 1 wave (2 waves/CU)
    dim3 block(64);
    snn_blocks_kernel<<<grid, block, 0, stream>>>(x, beta_raw, p_raw, b_raw, out);
}

// Round 2
// 232.801 us; speedup vs baseline: 1.0969x; 1.0969x over previous
//
#include <hip/hip_runtime.h>

// Blocks SNN forward: T=1024, TB=8, B=32, N=1024.
// One thread per (b,n) chain; 128 sequential time-blocks per thread.
// f64 state matches the harness's float64 reference on every heaviside
// decision (fp32 reassociation flips ~1e-7 margins).
//
// R9 = R7 memory scheme + R8 body + non-NT stores.
//  * R8 post-mortem: scalar dword loads/stores (16 vmem ops/body) + PF=4
//    regressed 87.6->101us. vmcnt is ONE in-order counter for loads and
//    stores: the s_waitcnt before consuming a frame can only be satisfied
//    when the OLDEST outstanding vmem ops retire - and those were
//    nontemporal stores draining to HBM (>1000cyc under write contention).
//    Frame-load waits were gated on NT-store retirement.
//  * Fix 1: back to dwordx4 loads + LDS lane-transpose, PF=8 (4 vmem
//    ops/body, frame age ~8 bodies) - R7's proven scheme.
//  * Fix 2: stores are REGULAR (not nontemporal): they ack at L2
//    write-back (~200cyc) instead of HBM, decoupling the in-order vmcnt
//    wait from the HBM write drain. L2 absorbs the 134MB stream.
//  * Keep R8's first-spike closed form: z[t]=sum(t-s+1)f[s] => z==1 only
//    at the first set bit of faulty; decay=first^7, ssum=p^(first+1),
//    refractory mask=(1<<first)-1, spike=one-hot. Integer-exact, saves
//    ~10 VALU ops x 8 t per block vs the cumsum pipeline.
// Occupancy is grid-bound (512 waves = 0.5/SIMD): every stall is exposed,
// so the whole game is shortening the per-body serial path.

constexpr int T_LEN = 1024;
constexpr int TB    = 8;
constexpr int NBLK  = T_LEN / TB;   // 128
constexpr int BATCH = 32;
constexpr int NOUT  = 1024;
constexpr int BN    = BATCH * NOUT; // 32768 chains
constexpr int PF    = 8;            // prefetch depth (blocks) = frame count

typedef float f4 __attribute__((ext_vector_type(4)));

__global__ __launch_bounds__(64, 1)
void snn_blocks_kernel(const float* __restrict__ x,
                       const float* __restrict__ beta_raw,
                       const float* __restrict__ p_raw,
                       const float* __restrict__ b_raw,
                       float* __restrict__ out)
{
    __shared__ float inbuf[TB][64];   // 2KB: load-transpose staging
    __shared__ float sbuf[TB][64];    // 2KB: store-transpose staging

    const int lane = threadIdx.x;
    const int wg0  = blockIdx.x * 64;       // flat chain offset of this WG
    const int gid  = wg0 + lane;            // = b*NOUT + n
    const int n    = gid & (NOUT - 1);

    // 16B-per-lane split: lane i handles row (i>>4) [+4 for 2nd op],
    // cols (i&15)*4..+3 of the 64-chain stripe.
    const int rowoff = lane >> 4;
    const int coloff = wg0 + (lane & 15) * 4;

    // clamped properties (f64)
    double beta = (double)beta_raw[n];
    beta = beta < 0.001 ? 0.001 : (beta > 0.999 ? 0.999 : beta);
    double p = fabs((double)p_raw[n]);
    p = p > 0.999 ? 0.999 : p;
    double bb = fabs((double)b_raw[n]);
    bb = bb < 0.001 ? 0.001 : (bb > 1.0 ? 1.0 : bb);
    const double inv_p = 1.0 / p;

    double ppow[9];                 // p^0 .. p^8 (compile-time indexed only)
    ppow[0] = 1.0;
#pragma unroll
    for (int i = 1; i <= 8; ++i) ppow[i] = ppow[i - 1] * p;

    double bbp[8];                  // bb * p^(t+1)
#pragma unroll
    for (int t = 0; t < 8; ++t) bbp[t] = bb * ppow[t + 1];

    const double pp2 = ppow[2], pp4 = ppow[4], pp8 = ppow[8];

    // carry state
    double m = 0.0;                 // running membrane / int_mem
    double a = 0.0;                 // a_kernel scalar (a_k[t] = p^(t+1)*a)
    int maskf  = 0;                 // any spike (z==1) in prev block
    int firstp = 0;                 // first-spike index of prev block

    // rotating register frame file (constant-indexed after unrolling)
    f4 fr[PF][2];

    const float* xbase = x + (ptrdiff_t)rowoff * BN + coloff;
    float* obase       = out + (ptrdiff_t)rowoff * BN + coloff;

    // preamble: issue loads for blocks 0..PF-1 (2 x dwordx4 per block)
#pragma unroll
    for (int k = 0; k < PF; ++k) {
        fr[k][0] = *(const f4*)(xbase + (ptrdiff_t)(k * TB) * BN);
        fr[k][1] = *(const f4*)(xbase + (ptrdiff_t)(k * TB + 4) * BN);
    }

#pragma unroll 1
    for (int r = 0; r < NBLK / PF; ++r) {
#pragma unroll
        for (int i = 0; i < PF; ++i) {
            const int blk = r * PF + i;

            // frame -> per-chain transpose via LDS. The ds_write is where
            // the compiler's vmcnt wait for this frame lands; with PF=8 and
            // 4 vmem ops/body the frame loads are ~8 bodies (~6-10K cyc)
            // old, and older stores ack fast at L2 (non-NT).
            *(f4*)&inbuf[rowoff][(lane & 15) * 4]     = fr[i][0];
            *(f4*)&inbuf[rowoff + 4][(lane & 15) * 4] = fr[i][1];

            // prefetch immediately after the frame regs die (ds_write has
            // consumed them) -> maximum load age before first use.
            const int pfb = blk + PF;
            if (pfb < NBLK) {
                fr[i][0] = *(const f4*)(xbase + (ptrdiff_t)(pfb * TB) * BN);
                fr[i][1] = *(const f4*)(xbase + (ptrdiff_t)(pfb * TB + 4) * BN);
            }

            float cur[8];
#pragma unroll
            for (int t = 0; t < 8; ++t) cur[t] = inbuf[t][lane];

            // ---- header: adaptation update from prev-block stats ----
            // ssum = p^(firstp+1); p^decay with decay = 7-firstp = firstp^7
            double pf1 = p;                        // -> p^(firstp+1)
            pf1 *= (firstp & 1) ? p   : 1.0;
            pf1 *= (firstp & 2) ? pp2 : 1.0;
            pf1 *= (firstp & 4) ? pp4 : 1.0;
            const int dsteps = firstp ^ 7;         // 7 - firstp
            double pd = (dsteps & 1) ? p : 1.0;
            pd *= (dsteps & 2) ? pp2 : 1.0;
            pd *= (dsteps & 4) ? pp4 : 1.0;
            const double new_a = (a * pf1 + inv_p) * pd;
            double vinit;
            if (maskf) { a = new_a;   vinit = 0.0; }  // v_init = 0
            else       { a = pp8 * a; vinit = m;   }  // keep int_mem

            // refractory mask: prev z[t]==0  <=>  t < firstp (when maskf)
            const int zmask = maskf ? ((1 << firstp) - 1) : 0;

            int fbits = 0;
            double mm = vinit;
#pragma unroll
            for (int t = 0; t < 8; ++t) {
                const float xf = ((zmask >> t) & 1) ? 0.0f : cur[t];
                mm = beta * mm + (double)xf;           // causal decayed sum
                const double vth = 1.0 + bbp[t] * a;   // 1 + bb*p^(t+1)*a
                fbits |= (mm - vth > 0.0) ? (1 << t) : 0;  // heaviside
            }
            m = mm;
            maskf  = (fbits != 0);
            firstp = fbits ? __builtin_ctz(fbits) : 0;

            // ---- stage spikes (one-hot at firstp), lane-transpose, store.
            // Regular stores (NOT nontemporal): ack at L2 write-back, so
            // they never become the oldest-outstanding vmcnt blocker.
#pragma unroll
            for (int t = 0; t < 8; ++t)
                sbuf[t][lane] = (maskf && t == firstp) ? 1.0f : 0.0f;

            const float* sflat = &sbuf[0][0];
            f4 s0 = *(const f4*)(sflat + lane * 4);
            f4 s1 = *(const f4*)(sflat + 256 + lane * 4);
            *(f4*)(obase + (ptrdiff_t)(blk * TB) * BN)     = s0;
            *(f4*)(obase + (ptrdiff_t)(blk * TB + 4) * BN) = s1;

            __builtin_amdgcn_sched_barrier(0);
        }
    }
}

extern "C" void kernel_launch(void* const* d_in, const int* in_sizes, int n_in,
                              void* d_out, int out_size, void* d_ws, size_t ws_size,
                              hipStream_t stream) {
    const float* x        = (const float*)d_in[0];
    const float* beta_raw = (const float*)d_in[1];
    const float* p_raw    = (const float*)d_in[2];
    const float* b_raw    = (const float*)d_in[3];
    float* out            = (float*)d_out;

    dim3 grid(BN / 64);   // 512 workgroups of 1 wave
    dim3 block(64);
    snn_blocks_kernel<<<grid, block, 0, stream>>>(x, beta_raw, p_raw, b_raw, out);
}